// Round 1
// baseline (78.183 us; speedup 1.0000x reference)
//
#include <hip/hip_runtime.h>

// SecondOrderFeatureInteraction: B=16384, F=27, D=128 fp32.
// out[b, p] = dot(in[b,i,:], in[b,j,:]) for pairs p = j*(j-1)/2 + i, i<j.
// One block per batch row; Gram via 4x4 register tiles x 8 d-slices.

#define F_ 27
#define FP_ 28          // rows padded to 28 (row 27 zeroed)
#define D_ 128
#define STRIDE_ 132     // LDS row stride in floats (128 + 4 pad -> row base shifts banks by 4)
#define NTILE_ 28       // 7*8/2 upper-tri 4x4 tiles over 28x28
#define NPAIR_ 351
#define PSTR_ 17        // partials stride (odd -> conflict-free scalar writes)

__global__ __launch_bounds__(256) void soi_kernel(const float* __restrict__ in,
                                                  float* __restrict__ out) {
    __shared__ float Xs[FP_ * STRIDE_];      // 3696 floats = 14.4 KB
    __shared__ float part[224 * PSTR_];      // 3808 floats = 14.9 KB

    const int b   = blockIdx.x;
    const int tid = threadIdx.x;
    const float* src = in + (size_t)b * (F_ * D_);

    // ---- stage global -> LDS (864 float4 chunks, coalesced) ----
    for (int g = tid; g < F_ * (D_ / 4); g += 256) {
        int row = g >> 5;      // /32 chunks per row
        int ch  = g & 31;
        float4 v = reinterpret_cast<const float4*>(src)[g];
        *reinterpret_cast<float4*>(&Xs[row * STRIDE_ + ch * 4]) = v;
    }
    // zero pad row 27
    for (int g = tid; g < STRIDE_; g += 256) Xs[27 * STRIDE_ + g] = 0.f;
    __syncthreads();

    // ---- compute: 28 tiles x 8 d-slices = 224 threads ----
    if (tid < NTILE_ * 8) {
        const int tdx = tid >> 3;
        const int s   = tid & 7;
        int ti = 0, rem = tdx;
        while (rem >= 7 - ti) { rem -= 7 - ti; ++ti; }
        const int tj = ti + rem;

        float acc[4][4];
        #pragma unroll
        for (int x = 0; x < 4; ++x)
            #pragma unroll
            for (int y = 0; y < 4; ++y) acc[x][y] = 0.f;

        const float* Arow = &Xs[(ti * 4) * STRIDE_];
        const float* Brow = &Xs[(tj * 4) * STRIDE_];
        #pragma unroll
        for (int c = 0; c < 4; ++c) {
            const int off = (s + 8 * c) * 4;   // interleaved chunks: slices span all bank-quads
            float4 av[4], bv[4];
            #pragma unroll
            for (int r = 0; r < 4; ++r)
                av[r] = *reinterpret_cast<const float4*>(&Arow[r * STRIDE_ + off]);
            #pragma unroll
            for (int r = 0; r < 4; ++r)
                bv[r] = *reinterpret_cast<const float4*>(&Brow[r * STRIDE_ + off]);
            #pragma unroll
            for (int x = 0; x < 4; ++x)
                #pragma unroll
                for (int y = 0; y < 4; ++y)
                    acc[x][y] += av[x].x * bv[y].x + av[x].y * bv[y].y +
                                 av[x].z * bv[y].z + av[x].w * bv[y].w;
        }
        float* p = &part[tid * PSTR_];
        #pragma unroll
        for (int x = 0; x < 4; ++x)
            #pragma unroll
            for (int y = 0; y < 4; ++y) p[x * 4 + y] = acc[x][y];
    }
    __syncthreads();

    // ---- gather upper-tri entries, reduce 8 slices, coalesced store ----
    float* dst = out + (size_t)b * NPAIR_;
    for (int pidx = tid; pidx < NPAIR_; pidx += 256) {
        // decode pidx = j*(j-1)/2 + i, i<j
        int j = (int)((1.0f + sqrtf(1.0f + 8.0f * (float)pidx)) * 0.5f);
        if (j * (j - 1) / 2 > pidx) --j;
        while ((j + 1) * j / 2 <= pidx) ++j;
        const int i  = pidx - j * (j - 1) / 2;
        const int ti = i >> 2, tj = j >> 2;
        const int tdx = ti * 7 - ti * (ti - 1) / 2 + (tj - ti);
        const int a   = (i & 3) * 4 + (j & 3);
        float ssum = 0.f;
        #pragma unroll
        for (int s = 0; s < 8; ++s)
            ssum += part[(tdx * 8 + s) * PSTR_ + a];
        dst[pidx] = ssum;
    }
}

extern "C" void kernel_launch(void* const* d_in, const int* in_sizes, int n_in,
                              void* d_out, int out_size, void* d_ws, size_t ws_size,
                              hipStream_t stream) {
    const float* in = (const float*)d_in[0];
    float* out      = (float*)d_out;
    const int B     = in_sizes[0] / (F_ * D_);
    soi_kernel<<<dim3(B), dim3(256), 0, stream>>>(in, out);
}

// Round 2
// 75.725 us; speedup vs baseline: 1.0325x; 1.0325x over previous
//
#include <hip/hip_runtime.h>

// SecondOrderFeatureInteraction: B=16384, F=27, D=128 fp32.
// out[b, p] = dot(in[b,i,:], in[b,j,:]) for pairs p = j*(j-1)/2 + i, i<j.
// One block per batch row. Gram via 4x4 register tiles x 8 d-slices,
// slice reduction via shfl_xor (no big LDS partials buffer), packed-fp32 FMA.

#define F_ 27
#define D_ 128
#define STRIDE_ 132     // LDS row stride in floats (128 + 4 pad)
#define NTILE_ 28       // 7*8/2 upper-tri 4x4 tiles over 28x28
#define NPAIR_ 351
#define RSTR_ 17        // reduced-tile stride (odd -> conflict-free writes)

typedef __attribute__((ext_vector_type(2))) float f32x2;

__global__ __launch_bounds__(256) void soi_kernel(const float* __restrict__ in,
                                                  float* __restrict__ out) {
    __shared__ float Xs[28 * STRIDE_];       // 14.4 KB
    __shared__ float red[NTILE_ * RSTR_];    // 1.9 KB reduced tiles

    const int b   = blockIdx.x;
    const int tid = threadIdx.x;
    const float* src = in + (size_t)b * (F_ * D_);

    // ---- stage global -> LDS (864 float4 chunks, coalesced) ----
    for (int g = tid; g < F_ * (D_ / 4); g += 256) {
        int row = g >> 5;
        int ch  = g & 31;
        float4 v = reinterpret_cast<const float4*>(src)[g];
        *reinterpret_cast<float4*>(&Xs[row * STRIDE_ + ch * 4]) = v;
    }
    if (tid < STRIDE_) Xs[27 * STRIDE_ + tid] = 0.f;   // zero pad row 27
    __syncthreads();

    // ---- compute: 28 tiles x 8 d-slices = 224 threads ----
    if (tid < NTILE_ * 8) {
        const int tdx = tid >> 3;
        const int s   = tid & 7;
        int ti = 0, rem = tdx;
        while (rem >= 7 - ti) { rem -= 7 - ti; ++ti; }
        const int tj = ti + rem;

        f32x2 acc[4][4];
        #pragma unroll
        for (int x = 0; x < 4; ++x)
            #pragma unroll
            for (int y = 0; y < 4; ++y) acc[x][y] = (f32x2)(0.f);

        const float* Arow = &Xs[(ti * 4) * STRIDE_];
        const float* Brow = &Xs[(tj * 4) * STRIDE_];
        #pragma unroll
        for (int c = 0; c < 4; ++c) {
            const int off = (s + 8 * c) * 4;   // interleaved chunks across slices
            f32x2 alo[4], ahi[4], blo[4], bhi[4];
            #pragma unroll
            for (int r = 0; r < 4; ++r) {
                float4 v = *reinterpret_cast<const float4*>(&Arow[r * STRIDE_ + off]);
                alo[r] = (f32x2){v.x, v.y};
                ahi[r] = (f32x2){v.z, v.w};
            }
            #pragma unroll
            for (int r = 0; r < 4; ++r) {
                float4 v = *reinterpret_cast<const float4*>(&Brow[r * STRIDE_ + off]);
                blo[r] = (f32x2){v.x, v.y};
                bhi[r] = (f32x2){v.z, v.w};
            }
            #pragma unroll
            for (int x = 0; x < 4; ++x)
                #pragma unroll
                for (int y = 0; y < 4; ++y)
                    acc[x][y] += alo[x] * blo[y] + ahi[x] * bhi[y];
        }

        // horizontal add then butterfly-reduce the 8 slices (masks stay in 8-group)
        float v16[16];
        #pragma unroll
        for (int x = 0; x < 4; ++x)
            #pragma unroll
            for (int y = 0; y < 4; ++y) v16[x * 4 + y] = acc[x][y].x + acc[x][y].y;
        #pragma unroll
        for (int m = 1; m <= 4; m <<= 1) {
            #pragma unroll
            for (int k = 0; k < 16; ++k) v16[k] += __shfl_xor(v16[k], m);
        }
        if (s == 0) {
            float* p = &red[tdx * RSTR_];
            #pragma unroll
            for (int k = 0; k < 16; ++k) p[k] = v16[k];
        }
    }
    __syncthreads();

    // ---- gather upper-tri entries, coalesced store ----
    float* dst = out + (size_t)b * NPAIR_;
    for (int pidx = tid; pidx < NPAIR_; pidx += 256) {
        int j = (int)((1.0f + sqrtf(1.0f + 8.0f * (float)pidx)) * 0.5f);
        if (j * (j - 1) / 2 > pidx) --j;
        while ((j + 1) * j / 2 <= pidx) ++j;
        const int i  = pidx - j * (j - 1) / 2;
        const int ti = i >> 2, tj = j >> 2;
        const int tdx = ti * 7 - ti * (ti - 1) / 2 + (tj - ti);
        const int a   = (i & 3) * 4 + (j & 3);
        dst[pidx] = red[tdx * RSTR_ + a];
    }
}

extern "C" void kernel_launch(void* const* d_in, const int* in_sizes, int n_in,
                              void* d_out, int out_size, void* d_ws, size_t ws_size,
                              hipStream_t stream) {
    const float* in = (const float*)d_in[0];
    float* out      = (float*)d_out;
    const int B     = in_sizes[0] / (F_ * D_);
    soi_kernel<<<dim3(B), dim3(256), 0, stream>>>(in, out);
}

// Round 3
// 45.328 us; speedup vs baseline: 1.7248x; 1.6706x over previous
//
#include <hip/hip_runtime.h>

// SecondOrderFeatureInteraction: B=16384, F=27, D=128 fp32.
// out[b, p] = dot(in[b,i,:], in[b,j,:]) for pairs p = j*(j-1)/2 + i, i<j.
// One block per batch row. Gram via MFMA 16x16x32 bf16 with hi/lo fp32 split:
// x = hi + lo (both bf16); dot = hi.hi + hi.lo + lo.hi (lo.lo ~5e-4, dropped).
// 3 waves own upper-tri 16x16 tiles (0,0),(0,1),(1,1) of the 32x32 Gram.

#define F_ 27
#define D_ 128
#define NPAIR_ 351
#define RW_ 136          // ushort row stride (272 B = 16B*17: odd 16B multiple)
#define GSTR_ 36         // Gram row stride in floats (144 B, 16B-aligned)

typedef __attribute__((ext_vector_type(8))) short short8;
typedef __attribute__((ext_vector_type(4))) float f32x4;
typedef __attribute__((ext_vector_type(4))) unsigned short ushort4v;

static __device__ inline unsigned short f2bf_rn(float x) {
    unsigned int u = __float_as_uint(x);
    unsigned int r = (u + 0x7fffu + ((u >> 16) & 1u)) >> 16;
    return (unsigned short)r;
}
static __device__ inline float bf2f(unsigned short h) {
    return __uint_as_float(((unsigned int)h) << 16);
}

__global__ __launch_bounds__(256) void soi_kernel(const float* __restrict__ in,
                                                  float* __restrict__ out) {
    __shared__ unsigned short Xhi[32 * RW_];   // 8.5 KB
    __shared__ unsigned short Xlo[32 * RW_];   // 8.5 KB
    __shared__ float G[32 * GSTR_];            // 4.5 KB

    const int b   = blockIdx.x;
    const int tid = threadIdx.x;
    const float* src = in + (size_t)b * (F_ * D_);

    // ---- stage global -> LDS bf16 hi/lo, XOR-swizzled 16B k-chunks ----
    for (int g = tid; g < F_ * (D_ / 4); g += 256) {
        const int r  = g >> 5;                 // 32 float4-chunks per row
        const int ch = g & 31;
        float4 v = reinterpret_cast<const float4*>(src)[g];
        const int c8   = ch >> 1;              // 16B bf16-chunk index [0,16)
        const int half = ch & 1;
        const int off  = r * RW_ + ((((c8 ^ (r & 15)) << 4) + (half << 3)) >> 1);
        unsigned short h0 = f2bf_rn(v.x), h1 = f2bf_rn(v.y),
                       h2 = f2bf_rn(v.z), h3 = f2bf_rn(v.w);
        ushort4v hv = {h0, h1, h2, h3};
        ushort4v lv = {f2bf_rn(v.x - bf2f(h0)), f2bf_rn(v.y - bf2f(h1)),
                       f2bf_rn(v.z - bf2f(h2)), f2bf_rn(v.w - bf2f(h3))};
        *reinterpret_cast<ushort4v*>(&Xhi[off]) = hv;
        *reinterpret_cast<ushort4v*>(&Xlo[off]) = lv;
    }
    // zero rows 27..31 (as uints; RW_ even)
    for (int z = tid; z < 5 * (RW_ / 2); z += 256) {
        const int r = 27 + z / (RW_ / 2);
        const int w = z % (RW_ / 2);
        reinterpret_cast<unsigned int*>(Xhi)[r * (RW_ / 2) + w] = 0u;
        reinterpret_cast<unsigned int*>(Xlo)[r * (RW_ / 2) + w] = 0u;
    }
    __syncthreads();

    // ---- MFMA Gram: wave w -> tile (ti,tj): 0->(0,0) 1->(0,1) 2->(1,1) ----
    const int wid = tid >> 6, lane = tid & 63;
    if (wid < 3) {
        const int ti = wid >> 1, tj = (wid + 1) >> 1;
        const int rl = lane & 15, kg = lane >> 4;
        const int rA = ti * 16 + rl, rB = tj * 16 + rl;

        short8 Ah[4], Al[4], Bh[4], Bl[4];
        #pragma unroll
        for (int s = 0; s < 4; ++s) {
            const int c8   = s * 4 + kg;                       // k-chunk of this frag
            const int offA = rA * RW_ + (((c8 ^ rl) << 4) >> 1);
            const int offB = rB * RW_ + (((c8 ^ rl) << 4) >> 1);
            Ah[s] = *reinterpret_cast<const short8*>(&Xhi[offA]);
            Al[s] = *reinterpret_cast<const short8*>(&Xlo[offA]);
            Bh[s] = *reinterpret_cast<const short8*>(&Xhi[offB]);
            Bl[s] = *reinterpret_cast<const short8*>(&Xlo[offB]);
        }
        f32x4 acc = {0.f, 0.f, 0.f, 0.f};
        #pragma unroll
        for (int s = 0; s < 4; ++s) {
            acc = __builtin_amdgcn_mfma_f32_16x16x32_bf16(Ah[s], Bh[s], acc, 0, 0, 0);
            acc = __builtin_amdgcn_mfma_f32_16x16x32_bf16(Ah[s], Bl[s], acc, 0, 0, 0);
            acc = __builtin_amdgcn_mfma_f32_16x16x32_bf16(Al[s], Bh[s], acc, 0, 0, 0);
        }
        // C layout (m89-verified): col=lane&15, row=(lane>>4)*4+reg.
        // Store transposed (Gram symmetric): G[tj*16+col][ti*16+rbase .. +3]
        const int gc = tj * 16 + (lane & 15);
        const int gr = ti * 16 + (lane >> 4) * 4;
        *reinterpret_cast<f32x4*>(&G[gc * GSTR_ + gr]) = acc;
    }
    __syncthreads();

    // ---- gather strictly-upper pairs: out[p] = G[j][i], p = j(j-1)/2 + i ----
    float* dst = out + (size_t)b * NPAIR_;
    for (int p = tid; p < NPAIR_; p += 256) {
        int j = (int)((1.0f + sqrtf(1.0f + 8.0f * (float)p)) * 0.5f);
        if (j * (j - 1) / 2 > p) --j;
        while ((j + 1) * j / 2 <= p) ++j;
        const int i = p - j * (j - 1) / 2;
        dst[p] = G[j * GSTR_ + i];
    }
}

extern "C" void kernel_launch(void* const* d_in, const int* in_sizes, int n_in,
                              void* d_out, int out_size, void* d_ws, size_t ws_size,
                              hipStream_t stream) {
    const float* in = (const float*)d_in[0];
    float* out      = (float*)d_out;
    const int B     = in_sizes[0] / (F_ * D_);
    soi_kernel<<<dim3(B), dim3(256), 0, stream>>>(in, out);
}

// Round 5
// 40.339 us; speedup vs baseline: 1.9382x; 1.1237x over previous
//
#include <hip/hip_runtime.h>
#include <hip/hip_bf16.h>

// SecondOrderFeatureInteraction: B=16384, F=27, D=128 fp32.
// out[b, p] = dot(in[b,i,:], in[b,j,:]) for pairs p = j*(j-1)/2 + i, i<j.
// One block per batch row. Gram via MFMA 16x16x32 bf16 with hi/lo fp32 split:
// x = hi + lo (both bf16); dot = hi.hi + hi.lo + lo.hi (lo.lo ~5e-7, dropped).
// 3 waves own upper-tri 16x16 tiles (0,0),(0,1),(1,1) of the 32x32 Gram.
// Row stride = 17 x 16B (odd quads) -> bank-balanced with NO xor swizzle.
// Conversion via __float22bfloat162_rn -> v_cvt_pk_bf16_f32 (packed, cheap).

#define F_ 27
#define D_ 128
#define NPAIR_ 351
#define RW_ 136          // ushort row stride = 272 B = 17 quads (odd)
#define GSTR_ 36         // Gram row stride in floats

typedef __attribute__((ext_vector_type(8))) short short8;
typedef __attribute__((ext_vector_type(4))) float f32x4;

static __device__ inline unsigned int pk_bf16(float a, float b) {
    float2 f2 = make_float2(a, b);
    __hip_bfloat162 h = __float22bfloat162_rn(f2);   // -> v_cvt_pk_bf16_f32
    unsigned int u;
    __builtin_memcpy(&u, &h, sizeof(u));
    return u;
}

__global__ __launch_bounds__(256) void soi_kernel(const float* __restrict__ in,
                                                  float* __restrict__ out) {
    __shared__ unsigned short Xhi[32 * RW_];   // 8.5 KB
    __shared__ unsigned short Xlo[32 * RW_];   // 8.5 KB
    __shared__ float G[32 * GSTR_];            // 4.5 KB

    const int b   = blockIdx.x;
    const int tid = threadIdx.x;
    const float* src = in + (size_t)b * (F_ * D_);

    // ---- stage: 216 threads x 64 B slabs (row r, float4-chunks 4q..4q+3) ----
    float4 v0, v1, v2, v3;
    const int r = tid >> 3, q = tid & 7;
    if (tid < 216) {
        const float4* s4 = reinterpret_cast<const float4*>(src) + (r * 32 + q * 4);
        v0 = s4[0]; v1 = s4[1]; v2 = s4[2]; v3 = s4[3];
    }
    // zero rows 27..31 of both buffers (overlaps global-load latency)
    {
        unsigned int* zh = reinterpret_cast<unsigned int*>(Xhi) + 27 * (RW_ / 2);
        unsigned int* zl = reinterpret_cast<unsigned int*>(Xlo) + 27 * (RW_ / 2);
        for (int z = tid; z < 5 * (RW_ / 2); z += 256) { zh[z] = 0u; zl[z] = 0u; }
    }
    if (tid < 216) {
        unsigned int h[8], l[8];
        const float4 vv[4] = {v0, v1, v2, v3};
        #pragma unroll
        for (int i = 0; i < 4; ++i) {
            const float4 v = vv[i];
            unsigned int h01 = pk_bf16(v.x, v.y);
            unsigned int h23 = pk_bf16(v.z, v.w);
            float l0 = v.x - __uint_as_float(h01 << 16);
            float l1 = v.y - __uint_as_float(h01 & 0xffff0000u);
            float l2 = v.z - __uint_as_float(h23 << 16);
            float l3 = v.w - __uint_as_float(h23 & 0xffff0000u);
            h[2 * i] = h01; h[2 * i + 1] = h23;
            l[2 * i] = pk_bf16(l0, l1); l[2 * i + 1] = pk_bf16(l2, l3);
        }
        const int ub = r * RW_ + q * 16;       // ushort offset, 16B-aligned
        *reinterpret_cast<uint4*>(&Xhi[ub])     = make_uint4(h[0], h[1], h[2], h[3]);
        *reinterpret_cast<uint4*>(&Xhi[ub + 8]) = make_uint4(h[4], h[5], h[6], h[7]);
        *reinterpret_cast<uint4*>(&Xlo[ub])     = make_uint4(l[0], l[1], l[2], l[3]);
        *reinterpret_cast<uint4*>(&Xlo[ub + 8]) = make_uint4(l[4], l[5], l[6], l[7]);
    }
    __syncthreads();

    // ---- MFMA Gram: wave w -> tile (ti,tj): 0->(0,0) 1->(0,1) 2->(1,1) ----
    const int wid = tid >> 6, lane = tid & 63;
    if (wid < 3) {
        const int ti = wid >> 1, tj = (wid + 1) >> 1;
        const int rl = lane & 15, kg = lane >> 4;
        const int rA = ti * 16 + rl, rB = tj * 16 + rl;

        short8 Ah[4], Al[4], Bh[4], Bl[4];
        #pragma unroll
        for (int s = 0; s < 4; ++s) {
            const int offA = rA * RW_ + (s * 4 + kg) * 8;   // ushort units (16B frag)
            const int offB = rB * RW_ + (s * 4 + kg) * 8;
            Ah[s] = *reinterpret_cast<const short8*>(&Xhi[offA]);
            Al[s] = *reinterpret_cast<const short8*>(&Xlo[offA]);
            Bh[s] = *reinterpret_cast<const short8*>(&Xhi[offB]);
            Bl[s] = *reinterpret_cast<const short8*>(&Xlo[offB]);
        }
        f32x4 acc = {0.f, 0.f, 0.f, 0.f};
        #pragma unroll
        for (int s = 0; s < 4; ++s) {
            acc = __builtin_amdgcn_mfma_f32_16x16x32_bf16(Ah[s], Bh[s], acc, 0, 0, 0);
            acc = __builtin_amdgcn_mfma_f32_16x16x32_bf16(Ah[s], Bl[s], acc, 0, 0, 0);
            acc = __builtin_amdgcn_mfma_f32_16x16x32_bf16(Al[s], Bh[s], acc, 0, 0, 0);
        }
        // C layout (m89): col=lane&15, row=(lane>>4)*4+reg. Store transposed
        // (Gram symmetric): G[tj*16+col][ti*16+rowbase .. +3]
        const int gc = tj * 16 + (lane & 15);
        const int gr = ti * 16 + (lane >> 4) * 4;
        *reinterpret_cast<f32x4*>(&G[gc * GSTR_ + gr]) = acc;
    }
    __syncthreads();

    // ---- gather strictly-upper pairs: out[p] = G[j][i], p = j(j-1)/2 + i ----
    float* dst = out + (size_t)b * NPAIR_;
    for (int p = tid; p < NPAIR_; p += 256) {
        int j = (int)((1.0f + sqrtf(1.0f + 8.0f * (float)p)) * 0.5f);
        if (j * (j - 1) / 2 > p) --j;
        while ((j + 1) * j / 2 <= p) ++j;
        const int i = p - j * (j - 1) / 2;
        dst[p] = G[j * GSTR_ + i];
    }
}

extern "C" void kernel_launch(void* const* d_in, const int* in_sizes, int n_in,
                              void* d_out, int out_size, void* d_ws, size_t ws_size,
                              hipStream_t stream) {
    const float* in = (const float*)d_in[0];
    float* out      = (float*)d_out;
    const int B     = in_sizes[0] / (F_ * D_);
    soi_kernel<<<dim3(B), dim3(256), 0, stream>>>(in, out);
}